// Round 17
// baseline (59.783 us; speedup 1.0000x reference)
//
#include <hip/hip_runtime.h>
#include <hip/hip_bf16.h>

// out[k,s] = sum_{g: seq[g]==k} exp(A[gi,s] + 1 - pos[g]*B[gi,s]),
// N=1000, S=32, M=2M, K=100k.
//
// Round 17. Reduce-shape edits r14-r16 all neutral -> reduce is not the
// dominant term. Cost model says partition's flush scatter line-txns
// (245 blk x 782 runs x ~1.7 lines ~ 325K @ ~15G lines/s ~ 20us) is the
// largest single cost. Fix: CHUNK 8192->16384 (123 blocks, runs of ~21
// entries ~ 2.3 lines) -> ~220K txns. (bucket,rank) packed into one int
// to hold 16 entries/thread without spills. Reduce = r13 exact (best
// measured). Prep unchanged.

#define CHUNK 16384       // genes per partition block (16/thread @ 1024t)
#define NBMAX 1024        // max 128-seq buckets (K <= 131072)
#define CAPLG 12          // per-bucket region = 4096 entries
#define CAP   (1 << CAPLG)
#define SCAP  3072        // sorted capacity per half-region (mean fill 1280)

__device__ inline float fast_exp2(float x) {
    float r;
    asm("v_exp_f32 %0, %1" : "=v"(r) : "v"(x));
    return r;
}

// ---- 0: pack AB2p[gi*32+s] = f16((A+1)*log2e) | bf16(B*log2e/2^15)<<16
//         and zero gcur[NBMAX]
__global__ __launch_bounds__(256) void prep_kernel(
    const float* __restrict__ A, const float* __restrict__ B,
    unsigned* __restrict__ AB2p, int* __restrict__ gcur, int NS)
{
    const int i = blockIdx.x * 256 + threadIdx.x;
    if (i < NBMAX) gcur[i] = 0;
    if (i >= NS) return;
    const float a2 = (A[i] + 1.0f) * 1.44269504f;
    const float b2 = B[i] * (1.44269504f / 32768.0f);
    const _Float16 ha = (_Float16)a2;                       // RNE cvt
    const unsigned short ua = __builtin_bit_cast(unsigned short, ha);
    unsigned bb = __float_as_uint(b2);
    bb = (bb + 0x7FFFu + ((bb >> 16) & 1u)) & 0xFFFF0000u;  // RNE to bf16
    AB2p[i] = (unsigned)ua | bb;
}

// ---- 1: partition (CHUNK 16384): rank-in-register sort + claim + run flush
__global__ __launch_bounds__(1024) void partition_kernel(
    const float* __restrict__ pos, const int* __restrict__ gidx,
    const int* __restrict__ sidx, int* __restrict__ gcur,
    unsigned* __restrict__ payload, int M, int NB)
{
    __shared__ int h[NBMAX];                 // 4 KB
    __shared__ int pfx[NBMAX];               // 4 KB
    __shared__ int dbase[NBMAX];             // 4 KB
    __shared__ int wsum[16];
    __shared__ unsigned stg_p[CHUNK];        // 64 KB packed payload
    const int t = threadIdx.x, blk = blockIdx.x;
    const int i0 = blk * CHUNK;
    const int n = min(CHUNK, M - i0);
    const int l16 = t & 15, grp16 = t >> 4;  // 64 groups of 16

    h[t] = 0;
    __syncthreads();

    // single pass: load tuples, pack payload, hist+rank.
    // rkbb = bucket(10b) << 18 | rank(18b); -1 = invalid.
    unsigned pl[16];
    int rkbb[16];
#pragma unroll
    for (int u = 0; u < 16; u++) {
        const int j = t + u * 1024;
        rkbb[u] = -1;
        if (j < n) {
            const int sx = sidx[i0 + j];
            const int b = sx >> 7;
            const float p = pos[i0 + j];
            int q = (int)fmaf(p, 32768.0f, 0.5f);
            q = min(q, 32767);
            pl[u] = (unsigned)(sx & 127)
                  | ((unsigned)gidx[i0 + j] << 7)
                  | ((unsigned)q << 17);
            rkbb[u] = (b << 18) | atomicAdd(&h[b], 1);
        }
    }
    __syncthreads();

    // block-wide exclusive scan over 1024 bins (wave shfl + wave sums)
    {
        const int v = h[t];
        int incl = v;
#pragma unroll
        for (int d = 1; d < 64; d <<= 1) {
            const int x = __shfl_up(incl, d);
            if ((t & 63) >= d) incl += x;
        }
        if ((t & 63) == 63) wsum[t >> 6] = incl;
        __syncthreads();
        if (t < 16) {
            const int wv = wsum[t];
            int winc = wv;
#pragma unroll
            for (int d = 1; d < 16; d <<= 1) {
                const int x = __shfl_up(winc, d, 16);
                if (t >= d) winc += x;
            }
            wsum[t] = winc - wv;
        }
        __syncthreads();
        pfx[t] = wsum[t >> 6] + incl - v;
    }
    __syncthreads();

    // staging scatter using register ranks (plain ds_write, no atomics)
#pragma unroll
    for (int u = 0; u < 16; u++)
        if (rkbb[u] >= 0)
            stg_p[pfx[rkbb[u] >> 18] + (rkbb[u] & 0x3FFFF)] = pl[u];

    // claim this block's range in each bucket's fixed region
    if (t < NB) {
        const int hc = h[t];
        int dst = t << CAPLG;
        if (hc > 0) dst += atomicAdd(&gcur[t], hc);
        dbase[t] = dst;
    }
    __syncthreads();

    // run-based flush: one 16-lane group per bucket-run (~21 entries)
    for (int b = grp16; b < NB; b += 64) {
        const int cnt = h[b];
        if (cnt == 0) continue;
        const int src = pfx[b];
        const int dst = dbase[b];
        for (int i = l16; i < cnt; i += 16) {
            const int rr = dst + i;
            if ((rr >> CAPLG) == b) payload[rr] = stg_p[src + i];
        }
    }
}

// ---- 2: fused half-region sort-by-seq + 16-lane-group register reduce -----
// (r13 exact: 512t, 8 waves, single-level rank, 64-seq half per block)
__global__ __launch_bounds__(512) void fused_reduce_kernel(
    const unsigned* __restrict__ AB2p, const unsigned* __restrict__ payload,
    const int* __restrict__ gcur, float* __restrict__ out, int K)
{
    __shared__ unsigned sorted[SCAP + 8];   // +8: tail over-read slack
    __shared__ int h[64];
    __shared__ int pfx[64];
    const int t = threadIdx.x;
    const int bkt = blockIdx.x >> 1;    // 128-seq region
    const int sp  = blockIdx.x & 1;     // which 64-seq half
    const int g4  = (t >> 4) & 3;       // gene slot within wave (0..3)
    const int l16 = t & 15;             // sample-pair id
    const unsigned lane8 = (unsigned)(l16 << 3);
    const int wv = t >> 6;              // wave id 0..7
    const int start = bkt << CAPLG;
    const int n = min(gcur[bkt], CAP);

    if (t < 64) h[t] = 0;
    __syncthreads();

    // load full region (8/thread), keep my half; rank-in-register
    unsigned r[8];
    int rk[8];
#pragma unroll
    for (int u = 0; u < 8; u++) {
        const int idx = t + u * 512;
        rk[u] = -1;
        if (idx < n) {
            const unsigned w = payload[start + idx];
            if (((w >> 6) & 1u) == (unsigned)sp) {
                r[u] = w;
                rk[u] = atomicAdd(&h[w & 63], 1);
            }
        }
    }
    __syncthreads();

    // 64-bin exclusive scan by wave 0
    if (t < 64) {
        const int v = h[t];
        int incl = v;
#pragma unroll
        for (int d = 1; d < 64; d <<= 1) {
            const int x = __shfl_up(incl, d);
            if (t >= d) incl += x;
        }
        pfx[t] = incl - v;
    }
    __syncthreads();

    // scatter: plain ds_write; guard vs SCAP overflow
#pragma unroll
    for (int u = 0; u < 8; u++)
        if (rk[u] >= 0) {
            const int d = pfx[r[u] & 63] + rk[u];
            if (d < SCAP) sorted[d] = r[u];
        }
    __syncthreads();

    // accumulate: 4 genes per quad (16 lanes each), 2 quads in flight
#define GPROC(gi, A0, A1)                                                     \
    {                                                                         \
        const unsigned w = sorted[gi];                                        \
        const bool valid = (gi) < e;                                          \
        const unsigned voff = (w & 0x1FF80u) | lane8;                         \
        const uint2 ab = *(const uint2*)((const char*)AB2p + voff);           \
        const float qf = (float)(w >> 17);                                    \
        float fa0, fa1;                                                       \
        asm("v_cvt_f32_f16 %0, %1" : "=v"(fa0) : "v"(ab.x));                  \
        asm("v_cvt_f32_f16 %0, %1" : "=v"(fa1) : "v"(ab.y));                  \
        float x0 = fmaf(-qf, __int_as_float(ab.x & 0xFFFF0000u), fa0);        \
        float x1 = fmaf(-qf, __int_as_float(ab.y & 0xFFFF0000u), fa1);        \
        x0 = valid ? x0 : -2000.0f;                                           \
        x1 = valid ? x1 : -2000.0f;                                           \
        A0 += fast_exp2(x0);                                                  \
        A1 += fast_exp2(x1);                                                  \
    }

    const int seqbase = (bkt << 7) + (sp << 6) + (wv << 3);
    for (int q = 0; q < 8; q++) {
        const int ls = (wv << 3) + q;
        const int i0 = pfx[ls];
        const int e = min(i0 + h[ls], SCAP);
        float a0 = 0.0f, a1 = 0.0f, b0 = 0.0f, b1 = 0.0f;
        int i = i0;
        for (; i + 4 < e; i += 8) {
            GPROC(i + g4, a0, a1);
            GPROC(i + 4 + g4, b0, b1);
        }
        for (; i < e; i += 4)
            GPROC(i + g4, a0, a1);
        float acc0 = a0 + b0, acc1 = a1 + b1;
        acc0 += __shfl_xor(acc0, 16);
        acc1 += __shfl_xor(acc1, 16);
        acc0 += __shfl_xor(acc0, 32);
        acc1 += __shfl_xor(acc1, 32);
        const int seq = seqbase + q;
        if ((t & 48) == 0 && seq < K)
            *(float2*)&out[(seq << 5) + (l16 << 1)] = make_float2(acc0, acc1);
    }
#undef GPROC
}

// ---- fallback (round-1 atomic version) ------------------------------------
__global__ __launch_bounds__(256) void scatter_exp_fallback(
    const float* __restrict__ A, const float* __restrict__ B,
    const float* __restrict__ pos, const int* __restrict__ gidx,
    const int* __restrict__ sidx, float* __restrict__ out, int M)
{
    const int lane = threadIdx.x & 31;
    int group = (int)((blockIdx.x * blockDim.x + threadIdx.x) >> 5);
    const int stride = (int)((gridDim.x * blockDim.x) >> 5);
    for (int g = group; g < M; g += stride) {
        const int gi = gidx[g];
        const int si = sidx[g];
        const float p = pos[g];
        const float a = A[(gi << 5) + lane];
        const float b = B[(gi << 5) + lane];
        atomicAdd(&out[(si << 5) + lane], __expf(fmaf(-p, b, a + 1.0f)));
    }
}

extern "C" void kernel_launch(void* const* d_in, const int* in_sizes, int n_in,
                              void* d_out, int out_size, void* d_ws, size_t ws_size,
                              hipStream_t stream)
{
    const float* A    = (const float*)d_in[0];   // [N,32]
    const float* B    = (const float*)d_in[1];   // [N,32]
    const float* pos  = (const float*)d_in[2];   // [M]
    const int*   gidx = (const int*)d_in[3];     // [M]
    const int*   sidx = (const int*)d_in[4];     // [M]
    float*       out  = (float*)d_out;           // [K,32]

    const int M  = in_sizes[2];
    const int NS = in_sizes[0];                  // N*32
    const int N  = NS / 32;
    const int K  = out_size / 32;
    const int NB = (K + 127) >> 7;               // 782 for K=100k
    const int NBLK = (M + CHUNK - 1) / CHUNK;    // 123 for M=2M

    // ws layout: gcur i32[NBMAX] | AB2p u32[N*32] | payload u32[NB<<CAPLG]
    char* ws = (char*)d_ws;
    size_t off = 0;
    int* gcur = (int*)(ws + off);       off += (size_t)NBMAX * sizeof(int);
    off = (off + 255) & ~(size_t)255;
    unsigned* AB2p = (unsigned*)(ws + off); off += (size_t)N * 32 * sizeof(unsigned);
    off = (off + 255) & ~(size_t)255;
    unsigned* payload = (unsigned*)(ws + off);
    const size_t need = off + ((size_t)NB << CAPLG) * sizeof(unsigned);

    // pack limits: local seq 7b, gidx 10b (N<=1024), pos_q 15b, rank 18b;
    // mean bucket fill must be well under CAP (guarded writes handle tails)
    const bool packable = (NB <= NBMAX) && (K <= NBMAX * 128) && (N <= 1024)
                       && (M / (NB > 0 ? NB : 1) <= CAP / 4 * 3);
    if (!packable || ws_size < need) {
        hipMemsetAsync(d_out, 0, (size_t)out_size * sizeof(float), stream);
        scatter_exp_fallback<<<8192, 256, 0, stream>>>(A, B, pos, gidx, sidx, out, M);
        return;
    }

    const int prep_grid = (max(NS, NBMAX) + 255) / 256;
    prep_kernel     <<<prep_grid, 256, 0, stream>>>(A, B, AB2p, gcur, NS);
    partition_kernel<<<NBLK, 1024, 0, stream>>>(pos, gidx, sidx, gcur, payload, M, NB);
    fused_reduce_kernel<<<NB * 2, 512, 0, stream>>>(AB2p, payload, gcur, out, K);
}

// Round 18
// 57.208 us; speedup vs baseline: 1.0450x; 1.0450x over previous
//
#include <hip/hip_runtime.h>
#include <hip/hip_bf16.h>

// out[k,s] = sum_{g: seq[g]==k} exp(A[gi,s] + 1 - pos[g]*B[gi,s]),
// N=1000, S=32, M=2M, K=100k.
//
// FINAL (= round-13 configuration, best measured: 57.3us total, 3.6x over
// the naive atomic baseline's 206us).
// Pipeline: prep (pack A,B to one u32/[genome,sample] + zero claims) ->
// partition (1024t, CHUNK 8192: rank-in-register counting sort by 128-seq
// bucket, atomic range claim into fixed 4096-entry regions, coalesced run
// flush) -> fused reduce (512t per 64-seq half-region: rank sort by seq in
// LDS, then 16-lane gene quads gather the packed table via dwordx2 and
// accumulate exp2 in registers; shfl merge; float2 stores).
// Measured dead-ends (do not revisit): per-lane atomics (global 206us / LDS
// 375us), random line-writes ~15G/s (181us), short random read-gather
// (FETCH x7, 44us), LDS-resident table (occupancy loss, 57us reduce),
// 64-seq partition bins (2x flush txns), reduce shape variants (all ±2%).

#define CHUNK 8192        // genes per partition block
#define NBMAX 1024        // max 128-seq buckets (K <= 131072)
#define CAPLG 12          // per-bucket region = 4096 entries
#define CAP   (1 << CAPLG)
#define SCAP  3072        // sorted capacity per half-region (mean fill 1280)

__device__ inline float fast_exp2(float x) {
    float r;
    asm("v_exp_f32 %0, %1" : "=v"(r) : "v"(x));
    return r;
}

// ---- 0: pack AB2p[gi*32+s] = f16((A+1)*log2e) | bf16(B*log2e/2^15)<<16
//         and zero gcur[NBMAX]
__global__ __launch_bounds__(256) void prep_kernel(
    const float* __restrict__ A, const float* __restrict__ B,
    unsigned* __restrict__ AB2p, int* __restrict__ gcur, int NS)
{
    const int i = blockIdx.x * 256 + threadIdx.x;
    if (i < NBMAX) gcur[i] = 0;
    if (i >= NS) return;
    const float a2 = (A[i] + 1.0f) * 1.44269504f;
    const float b2 = B[i] * (1.44269504f / 32768.0f);
    const _Float16 ha = (_Float16)a2;                       // RNE cvt
    const unsigned short ua = __builtin_bit_cast(unsigned short, ha);
    unsigned bb = __float_as_uint(b2);
    bb = (bb + 0x7FFFu + ((bb >> 16) & 1u)) & 0xFFFF0000u;  // RNE to bf16
    AB2p[i] = (unsigned)ua | bb;
}

// ---- 1: partition, rank-in-register counting sort + atomic range claim ----
__global__ __launch_bounds__(1024) void partition_kernel(
    const float* __restrict__ pos, const int* __restrict__ gidx,
    const int* __restrict__ sidx, int* __restrict__ gcur,
    unsigned* __restrict__ payload, int M, int NB)
{
    __shared__ int h[NBMAX];
    __shared__ int pfx[NBMAX];
    __shared__ int dbase[NBMAX];
    __shared__ int wsum[16];
    __shared__ unsigned stg_p[CHUNK];        // 32 KB packed payload
    __shared__ unsigned short stg_b[CHUNK];  // 16 KB bucket of each slot
    const int t = threadIdx.x, blk = blockIdx.x;
    const int i0 = blk * CHUNK;
    const int n = min(CHUNK, M - i0);

    h[t] = 0;
    __syncthreads();

    // single pass: load tuples to registers, pack, hist+rank
    unsigned pl[8];
    int bb[8], rk[8];
#pragma unroll
    for (int u = 0; u < 8; u++) {
        const int j = t + u * 1024;
        rk[u] = -1;
        if (j < n) {
            const int sx = sidx[i0 + j];
            const int b = sx >> 7;
            const float p = pos[i0 + j];
            int q = (int)fmaf(p, 32768.0f, 0.5f);
            q = min(q, 32767);
            pl[u] = (unsigned)(sx & 127)
                  | ((unsigned)gidx[i0 + j] << 7)
                  | ((unsigned)q << 17);
            bb[u] = b;
            rk[u] = atomicAdd(&h[b], 1);
        }
    }
    __syncthreads();

    // block-wide exclusive scan over 1024 bins (wave shfl + wave sums)
    {
        const int v = h[t];
        int incl = v;
#pragma unroll
        for (int d = 1; d < 64; d <<= 1) {
            const int x = __shfl_up(incl, d);
            if ((t & 63) >= d) incl += x;
        }
        if ((t & 63) == 63) wsum[t >> 6] = incl;
        __syncthreads();
        if (t < 16) {
            const int wv = wsum[t];
            int winc = wv;
#pragma unroll
            for (int d = 1; d < 16; d <<= 1) {
                const int x = __shfl_up(winc, d, 16);
                if (t >= d) winc += x;
            }
            wsum[t] = winc - wv;
        }
        __syncthreads();
        pfx[t] = wsum[t >> 6] + incl - v;
    }
    __syncthreads();

    // staging scatter using register ranks (plain ds_write, no atomics)
#pragma unroll
    for (int u = 0; u < 8; u++)
        if (rk[u] >= 0) {
            const int d = pfx[bb[u]] + rk[u];
            stg_p[d] = pl[u];
            stg_b[d] = (unsigned short)bb[u];
        }
    __syncthreads();

    // claim this block's range in each bucket's fixed region
    if (t < NB) {
        const int hc = h[t];
        int dst = t << CAPLG;
        if (hc > 0) dst += atomicAdd(&gcur[t], hc);
        dbase[t] = dst;
    }
    __syncthreads();

    // coalesced flush; guard against (statistically impossible) overflow
    for (int tt = t; tt < n; tt += 1024) {
        const int b = stg_b[tt];
        const int r = dbase[b] + (tt - pfx[b]);
        if ((r >> CAPLG) == b) payload[r] = stg_p[tt];
    }
}

// ---- 2: fused half-region sort-by-seq + 16-lane-group register reduce -----
__global__ __launch_bounds__(512) void fused_reduce_kernel(
    const unsigned* __restrict__ AB2p, const unsigned* __restrict__ payload,
    const int* __restrict__ gcur, float* __restrict__ out, int K)
{
    __shared__ unsigned sorted[SCAP + 8];   // +8: tail over-read slack
    __shared__ int h[64];
    __shared__ int pfx[64];
    const int t = threadIdx.x;
    const int bkt = blockIdx.x >> 1;    // 128-seq region
    const int sp  = blockIdx.x & 1;     // which 64-seq half
    const int g4  = (t >> 4) & 3;       // gene slot within wave (0..3)
    const int l16 = t & 15;             // sample-pair id
    const unsigned lane8 = (unsigned)(l16 << 3);
    const int wv = t >> 6;              // wave id 0..7
    const int start = bkt << CAPLG;
    const int n = min(gcur[bkt], CAP);

    if (t < 64) h[t] = 0;
    __syncthreads();

    // load full region (8/thread), keep my half; rank-in-register
    unsigned r[8];
    int rk[8];
#pragma unroll
    for (int u = 0; u < 8; u++) {
        const int idx = t + u * 512;
        rk[u] = -1;
        if (idx < n) {
            const unsigned w = payload[start + idx];
            if (((w >> 6) & 1u) == (unsigned)sp) {
                r[u] = w;
                rk[u] = atomicAdd(&h[w & 63], 1);
            }
        }
    }
    __syncthreads();

    // 64-bin exclusive scan by wave 0
    if (t < 64) {
        const int v = h[t];
        int incl = v;
#pragma unroll
        for (int d = 1; d < 64; d <<= 1) {
            const int x = __shfl_up(incl, d);
            if (t >= d) incl += x;
        }
        pfx[t] = incl - v;
    }
    __syncthreads();

    // scatter: plain ds_write; guard vs SCAP overflow
#pragma unroll
    for (int u = 0; u < 8; u++)
        if (rk[u] >= 0) {
            const int d = pfx[r[u] & 63] + rk[u];
            if (d < SCAP) sorted[d] = r[u];
        }
    __syncthreads();

    // accumulate: 4 genes per quad (16 lanes each), 2 quads in flight
#define GPROC(gi, A0, A1)                                                     \
    {                                                                         \
        const unsigned w = sorted[gi];                                        \
        const bool valid = (gi) < e;                                          \
        const unsigned voff = (w & 0x1FF80u) | lane8;                         \
        const uint2 ab = *(const uint2*)((const char*)AB2p + voff);           \
        const float qf = (float)(w >> 17);                                    \
        float fa0, fa1;                                                       \
        asm("v_cvt_f32_f16 %0, %1" : "=v"(fa0) : "v"(ab.x));                  \
        asm("v_cvt_f32_f16 %0, %1" : "=v"(fa1) : "v"(ab.y));                  \
        float x0 = fmaf(-qf, __int_as_float(ab.x & 0xFFFF0000u), fa0);        \
        float x1 = fmaf(-qf, __int_as_float(ab.y & 0xFFFF0000u), fa1);        \
        x0 = valid ? x0 : -2000.0f;                                           \
        x1 = valid ? x1 : -2000.0f;                                           \
        A0 += fast_exp2(x0);                                                  \
        A1 += fast_exp2(x1);                                                  \
    }

    const int seqbase = (bkt << 7) + (sp << 6) + (wv << 3);
    for (int q = 0; q < 8; q++) {
        const int ls = (wv << 3) + q;
        const int i0 = pfx[ls];
        const int e = min(i0 + h[ls], SCAP);
        float a0 = 0.0f, a1 = 0.0f, b0 = 0.0f, b1 = 0.0f;
        int i = i0;
        for (; i + 4 < e; i += 8) {
            GPROC(i + g4, a0, a1);
            GPROC(i + 4 + g4, b0, b1);
        }
        for (; i < e; i += 4)
            GPROC(i + g4, a0, a1);
        float acc0 = a0 + b0, acc1 = a1 + b1;
        acc0 += __shfl_xor(acc0, 16);
        acc1 += __shfl_xor(acc1, 16);
        acc0 += __shfl_xor(acc0, 32);
        acc1 += __shfl_xor(acc1, 32);
        const int seq = seqbase + q;
        if ((t & 48) == 0 && seq < K)
            *(float2*)&out[(seq << 5) + (l16 << 1)] = make_float2(acc0, acc1);
    }
#undef GPROC
}

// ---- fallback (round-1 atomic version) ------------------------------------
__global__ __launch_bounds__(256) void scatter_exp_fallback(
    const float* __restrict__ A, const float* __restrict__ B,
    const float* __restrict__ pos, const int* __restrict__ gidx,
    const int* __restrict__ sidx, float* __restrict__ out, int M)
{
    const int lane = threadIdx.x & 31;
    int group = (int)((blockIdx.x * blockDim.x + threadIdx.x) >> 5);
    const int stride = (int)((gridDim.x * blockDim.x) >> 5);
    for (int g = group; g < M; g += stride) {
        const int gi = gidx[g];
        const int si = sidx[g];
        const float p = pos[g];
        const float a = A[(gi << 5) + lane];
        const float b = B[(gi << 5) + lane];
        atomicAdd(&out[(si << 5) + lane], __expf(fmaf(-p, b, a + 1.0f)));
    }
}

extern "C" void kernel_launch(void* const* d_in, const int* in_sizes, int n_in,
                              void* d_out, int out_size, void* d_ws, size_t ws_size,
                              hipStream_t stream)
{
    const float* A    = (const float*)d_in[0];   // [N,32]
    const float* B    = (const float*)d_in[1];   // [N,32]
    const float* pos  = (const float*)d_in[2];   // [M]
    const int*   gidx = (const int*)d_in[3];     // [M]
    const int*   sidx = (const int*)d_in[4];     // [M]
    float*       out  = (float*)d_out;           // [K,32]

    const int M  = in_sizes[2];
    const int NS = in_sizes[0];                  // N*32
    const int N  = NS / 32;
    const int K  = out_size / 32;
    const int NB = (K + 127) >> 7;               // 782 for K=100k
    const int NBLK = (M + CHUNK - 1) / CHUNK;    // 245 for M=2M

    // ws layout: gcur i32[NBMAX] | AB2p u32[N*32] | payload u32[NB<<CAPLG]
    char* ws = (char*)d_ws;
    size_t off = 0;
    int* gcur = (int*)(ws + off);       off += (size_t)NBMAX * sizeof(int);
    off = (off + 255) & ~(size_t)255;
    unsigned* AB2p = (unsigned*)(ws + off); off += (size_t)N * 32 * sizeof(unsigned);
    off = (off + 255) & ~(size_t)255;
    unsigned* payload = (unsigned*)(ws + off);
    const size_t need = off + ((size_t)NB << CAPLG) * sizeof(unsigned);

    // pack limits: local seq 7b, gidx 10b (N<=1024), pos_q 15b; mean bucket
    // fill must be well under CAP (guarded writes handle the tail)
    const bool packable = (NB <= NBMAX) && (K <= NBMAX * 128) && (N <= 1024)
                       && (M / (NB > 0 ? NB : 1) <= CAP / 4 * 3);
    if (!packable || ws_size < need) {
        hipMemsetAsync(d_out, 0, (size_t)out_size * sizeof(float), stream);
        scatter_exp_fallback<<<8192, 256, 0, stream>>>(A, B, pos, gidx, sidx, out, M);
        return;
    }

    const int prep_grid = (max(NS, NBMAX) + 255) / 256;
    prep_kernel     <<<prep_grid, 256, 0, stream>>>(A, B, AB2p, gcur, NS);
    partition_kernel<<<NBLK, 1024, 0, stream>>>(pos, gidx, sidx, gcur, payload, M, NB);
    fused_reduce_kernel<<<NB * 2, 512, 0, stream>>>(AB2p, payload, gcur, out, K);
}